// Round 8
// baseline (1519.545 us; speedup 1.0000x reference)
//
#include <hip/hip_runtime.h>
#include <stdint.h>

typedef unsigned short u16;
typedef unsigned int u32;
typedef __attribute__((ext_vector_type(8))) __bf16 bf16x8;
typedef __attribute__((ext_vector_type(4))) float f32x4;

#define DEVINL static __device__ __forceinline__

// round-to-nearest-even f32 -> bf16
DEVINL u16 f2bf(float x) {
  u32 u = __float_as_uint(x);
  return (u16)((u + (((u >> 16) & 1u) + 0x7fffu)) >> 16);
}
DEVINL float bf2f(u16 h) { return __uint_as_float(((u32)h) << 16); }

// async global->LDS, 16B per lane. HW semantics: wave-uniform base + lane*16.
DEVINL void async16(const void* g, void* l) {
  void* g2 = const_cast<void*>(g);
  __builtin_amdgcn_global_load_lds((__attribute__((address_space(1))) void*)g2,
                                   (__attribute__((address_space(3))) void*)l,
                                   16, 0, 0);
}

// bijective XCD-aware block swizzle (m204 form).
DEVINL void swz_xy(int& bx, int& by) {
  const int gx = (int)gridDim.x;
  const int nwg = gx * (int)gridDim.y;
  const int bid = (int)blockIdx.y * gx + (int)blockIdx.x;
  const int q = nwg >> 3, r = nwg & 7, x = bid & 7, t = bid >> 3;
  const int s = (x < r ? x * (q + 1) : r * (q + 1) + (x - r) * q) + t;
  bx = s % gx;
  by = s / gx;
}

// LDS bank-conflict swizzle (both-sides rule): physical 16B slot =
// logical slot ^ ((row>>1)&3). Staging keeps LDS dest linear and permutes
// the GLOBAL source slot; fragment reads apply the same XOR.

// ============================ pack kernels ============================
__global__ void k_pack_w(const float* src, int n, int k, u16* hi, u16* lo,
                         int KP, long total, int gap) {
  long i = (long)blockIdx.x * 256 + threadIdx.x;
  if (i >= total) return;
  int r = (int)(i / KP);
  int c = (int)(i - (long)r * KP);
  int sc = c;
  bool ok = (r < n);
  if (gap) {
    if (c >= 600 && c < 640) ok = false;
    else if (c >= 640) sc = c - 40;
  }
  if (sc >= k) ok = false;
  float x = ok ? src[(size_t)r * k + sc] : 0.f;
  u16 h = f2bf(x);
  hi[i] = h;
  if (lo) lo[i] = f2bf(x - bf2f(h));
}

__global__ void k_pack_bias(const float* src, int n, float* dst, int NP) {
  int i = blockIdx.x * 256 + threadIdx.x;
  if (i < NP) dst[i] = (i < n) ? src[i] : 0.f;
}

// ==== bb_process + concat(s, bb) -> combined[:, 0:640]; also writes ====
// ==== d_out cols 0..299 = s * mask                                   ====
__global__ void k_bb(const float* s_c, const float* ps_c, const float* bb_w,
                     const float* bb_b, const int* mask_s, u16* Chi, u16* Clo,
                     float* outp, int r0) {
  int rn = blockIdx.x;
  int grow = r0 + rn;
  int b = grow / 50;
  int n = grow - b * 50;
  float keep = (n < mask_s[b]) ? 1.f : 0.f;
  const float* p = ps_c + (size_t)rn * 4;
  float p0 = p[0], p1 = p[1], p2 = p[2], p3 = p[3];
  float sz0 = p2 - p0, sz1 = p3 - p1;
  float bin[10];
  bin[0] = p0; bin[1] = p1; bin[2] = p2; bin[3] = p3;
  bin[4] = sz0; bin[5] = sz1;
  bin[6] = p0 + 0.5f * sz0; bin[7] = p1 + 0.5f * sz1;
  bin[8] = sz0 * sz1; bin[9] = sz0 / (sz1 + 1e-14f);
  for (int c = threadIdx.x; c < 640; c += 256) {
    float x = 0.f;
    if (c < 300) {
      x = s_c[(size_t)rn * 300 + c];
      outp[(size_t)grow * 600 + c] = keep * x;
    } else if (c < 600) {
      int j = c - 300;
      float a = bb_b[j];
      const float* wr = bb_w + j * 10;
#pragma unroll
      for (int kk = 0; kk < 10; ++kk) a += bin[kk] * wr[kk];
      x = fmaxf(a, 0.f);
    }
    u16 h = f2bf(x);
    Chi[(size_t)rn * 1280 + c] = h;
    Clo[(size_t)rn * 1280 + c] = f2bf(x - bf2f(h));
  }
}

// ============================ GEMM cores ============================

// Fused 3-product core (lp only): acc += Ah*Bh + Al*Bh + Ah*Bl.
// Two 16KB half-phases per K-step over 4 half-buffers (64KB, 2 blocks/CU),
// counted vmcnt(8).
DEVINL void gemm_fused3(const u16* Ahp, const u16* Alp, const u16* Bhp,
                        const u16* Blp, int lda, int ldw, int ksteps,
                        u16* S, f32x4 (&acc)[4][4]) {
  const int tid = threadIdx.x;
  const int lane = tid & 63;
  const int wv = tid >> 6;
  const int wr = (wv >> 1) * 64;
  const int wc = (wv & 1) * 64;
  const int mrow = lane & 15;
  const int q = lane >> 4;

  const int c0 = tid, c1 = tid + 256;
  const int p0 = ((c0 & 3) ^ ((c0 >> 3) & 3)) * 8;  // swizzled src slot
  const int p1 = ((c1 & 3) ^ ((c1 >> 3) & 3)) * 8;
  const long ao0 = (long)(c0 >> 2) * lda + p0;
  const long ao1 = (long)(c1 >> 2) * lda + p1;
  const long bo0 = (long)(c0 >> 2) * ldw + p0;
  const long bo1 = (long)(c1 >> 2) * ldw + p1;

  int aoffs[4], boffs[4];
#pragma unroll
  for (int k = 0; k < 4; ++k) {
    const int ra = wr + mrow + 16 * k;
    const int rb = wc + mrow + 16 * k;
    aoffs[k] = ra * 32 + ((q ^ ((ra >> 1) & 3)) << 3);
    boffs[k] = rb * 32 + ((q ^ ((rb >> 1) & 3)) << 3);
  }

  auto issueF = [&](int ph) {
    const long ta = (long)(ph >> 1) * 32;
    const u16* sa = (ph & 1) ? Alp : Ahp;
    const u16* sb = (ph & 1) ? Blp : Bhp;
    u16* d = S + (ph & 3) * 8192;
    async16(sa + ta + ao0, d + c0 * 8);
    async16(sa + ta + ao1, d + c1 * 8);
    async16(sb + ta + bo0, d + 4096 + c0 * 8);
    async16(sb + ta + bo1, d + 4096 + c1 * 8);
  };

  const int total = 2 * ksteps;
  issueF(0); issueF(1); if (total > 2) issueF(2);
  bf16x8 ah[4], bh[4];
  for (int i = 0; i < ksteps; ++i) {
    {
      const int rem = total - 1 - 2 * i;
      if (rem >= 2)      asm volatile("s_waitcnt vmcnt(8)" ::: "memory");
      else               asm volatile("s_waitcnt vmcnt(4)" ::: "memory");
      __builtin_amdgcn_sched_barrier(0);
      __builtin_amdgcn_s_barrier();
      __builtin_amdgcn_sched_barrier(0);
      if (2 * i + 3 < total) issueF(2 * i + 3);
      const u16* hb = S + ((2 * i) & 3) * 8192;
#pragma unroll
      for (int k = 0; k < 4; ++k) {
        ah[k] = *(const bf16x8*)(hb + aoffs[k]);
        bh[k] = *(const bf16x8*)(hb + 4096 + boffs[k]);
      }
#pragma unroll
      for (int mi = 0; mi < 4; ++mi)
#pragma unroll
        for (int nj = 0; nj < 4; ++nj)
          acc[mi][nj] = __builtin_amdgcn_mfma_f32_16x16x32_bf16(
              ah[mi], bh[nj], acc[mi][nj], 0, 0, 0);
    }
    {
      const int rem = total - 2 - 2 * i;
      if (rem >= 2)      asm volatile("s_waitcnt vmcnt(8)" ::: "memory");
      else if (rem == 1) asm volatile("s_waitcnt vmcnt(4)" ::: "memory");
      else               asm volatile("s_waitcnt vmcnt(0)" ::: "memory");
      __builtin_amdgcn_sched_barrier(0);
      __builtin_amdgcn_s_barrier();
      __builtin_amdgcn_sched_barrier(0);
      if (2 * i + 4 < total) issueF(2 * i + 4);
      const u16* hb = S + ((2 * i + 1) & 3) * 8192;
      bf16x8 al[4], bl[4];
#pragma unroll
      for (int k = 0; k < 4; ++k) {
        al[k] = *(const bf16x8*)(hb + aoffs[k]);
        bl[k] = *(const bf16x8*)(hb + 4096 + boffs[k]);
      }
#pragma unroll
      for (int mi = 0; mi < 4; ++mi)
#pragma unroll
        for (int nj = 0; nj < 4; ++nj)
          acc[mi][nj] = __builtin_amdgcn_mfma_f32_16x16x32_bf16(
              al[mi], bh[nj], acc[mi][nj], 0, 0, 0);
#pragma unroll
      for (int mi = 0; mi < 4; ++mi)
#pragma unroll
        for (int nj = 0; nj < 4; ++nj)
          acc[mi][nj] = __builtin_amdgcn_mfma_f32_16x16x32_bf16(
              ah[mi], bl[nj], acc[mi][nj], 0, 0, 0);
    }
  }
}

// single-pass core (fa5, out): 4 slots (64KB), depth-3 counted vmcnt.
DEVINL void gemm_core1(const u16* Ab, const u16* Bb, int lda, int ldw,
                       int ksteps, u16* As, u16* Bs, f32x4 (&acc)[4][4]) {
  const int tid = threadIdx.x;
  const int lane = tid & 63;
  const int wv = tid >> 6;
  const int wr = (wv >> 1) * 64;
  const int wc = (wv & 1) * 64;
  const int mrow = lane & 15;
  const int q = lane >> 4;

  const int c0 = tid, c1 = tid + 256;
  const int p0 = ((c0 & 3) ^ ((c0 >> 3) & 3)) * 8;
  const int p1 = ((c1 & 3) ^ ((c1 >> 3) & 3)) * 8;
  const long ao0 = (long)(c0 >> 2) * lda + p0;
  const long ao1 = (long)(c1 >> 2) * lda + p1;
  const long bo0 = (long)(c0 >> 2) * ldw + p0;
  const long bo1 = (long)(c1 >> 2) * ldw + p1;

  int aoffs[4], boffs[4];
#pragma unroll
  for (int k = 0; k < 4; ++k) {
    const int ra = wr + mrow + 16 * k;
    const int rb = wc + mrow + 16 * k;
    aoffs[k] = ra * 32 + ((q ^ ((ra >> 1) & 3)) << 3);
    boffs[k] = rb * 32 + ((q ^ ((rb >> 1) & 3)) << 3);
  }

  auto issue = [&](int sl, int t) {
    const long ta = (long)t * 32;
    u16* dA = As + sl * 4096;
    u16* dB = Bs + sl * 4096;
    async16(Ab + ta + ao0, dA + c0 * 8);
    async16(Ab + ta + ao1, dA + c1 * 8);
    async16(Bb + ta + bo0, dB + c0 * 8);
    async16(Bb + ta + bo1, dB + c1 * 8);
  };

  const int npro = ksteps < 3 ? ksteps : 3;
  for (int j = 0; j < npro; ++j) issue(j, j);
  int cs = 0, is = 3;
  for (int i = 0; i < ksteps; ++i) {
    const int rem = ksteps - 1 - i;
    if (rem >= 2)      asm volatile("s_waitcnt vmcnt(8)" ::: "memory");
    else if (rem == 1) asm volatile("s_waitcnt vmcnt(4)" ::: "memory");
    else               asm volatile("s_waitcnt vmcnt(0)" ::: "memory");
    __builtin_amdgcn_sched_barrier(0);
    __builtin_amdgcn_s_barrier();
    __builtin_amdgcn_sched_barrier(0);
    if (i + 3 < ksteps) { issue(is, i + 3); is = (is + 1) & 3; }
    const u16* Sa = As + cs * 4096;
    const u16* Sb = Bs + cs * 4096;
    cs = (cs + 1) & 3;
    bf16x8 af[4], bv[4];
#pragma unroll
    for (int k = 0; k < 4; ++k) af[k] = *(const bf16x8*)(Sa + aoffs[k]);
#pragma unroll
    for (int k = 0; k < 4; ++k) bv[k] = *(const bf16x8*)(Sb + boffs[k]);
#pragma unroll
    for (int mi = 0; mi < 4; ++mi)
#pragma unroll
      for (int nj = 0; nj < 4; ++nj)
        acc[mi][nj] = __builtin_amdgcn_mfma_f32_16x16x32_bf16(
            af[mi], bv[nj], acc[mi][nj], 0, 0, 0);
  }
}

// dual-B variant (fa12): 3-pass, 3-slot depth-2 counted pipeline, swizzled.
DEVINL void gemm_core2(const u16* const Aph[3], const u16* const B1ph[3],
                       const u16* const B2ph[3], int lda, int ldw, int ksteps,
                       u16* As, u16* B1s, u16* B2s, f32x4 (&a1)[4][4],
                       f32x4 (&a2)[4][4]) {
  const int tid = threadIdx.x;
  const int lane = tid & 63;
  const int wv = tid >> 6;
  const int wr = (wv >> 1) * 64;
  const int wc = (wv & 1) * 64;
  const int mrow = lane & 15;
  const int q = lane >> 4;

  const int c0 = tid, c1 = tid + 256;
  const int p0 = ((c0 & 3) ^ ((c0 >> 3) & 3)) * 8;
  const int p1 = ((c1 & 3) ^ ((c1 >> 3) & 3)) * 8;
  const long ao0 = (long)(c0 >> 2) * lda + p0;
  const long ao1 = (long)(c1 >> 2) * lda + p1;
  const long bo0 = (long)(c0 >> 2) * ldw + p0;
  const long bo1 = (long)(c1 >> 2) * ldw + p1;

  int aoffs[4], boffs[4];
#pragma unroll
  for (int k = 0; k < 4; ++k) {
    const int ra = wr + mrow + 16 * k;
    const int rb = wc + mrow + 16 * k;
    aoffs[k] = ra * 32 + ((q ^ ((ra >> 1) & 3)) << 3);
    boffs[k] = rb * 32 + ((q ^ ((rb >> 1) & 3)) << 3);
  }

  const u16* Aa1 = Aph[1]; const u16* Ba1 = B1ph[1]; const u16* Ca1 = B2ph[1];
  const u16* Aa2 = Aph[2]; const u16* Ba2 = B1ph[2]; const u16* Ca2 = B2ph[2];
  const u16* An = Aph[0];  const u16* Bn = B1ph[0];  const u16* Cn = B2ph[0];
  int tn = 0, pn = 0;
  const int total = 3 * ksteps;

  auto issue = [&](int sl) {
    const u16* ga = An + (long)tn * 32;
    const u16* g1 = Bn + (long)tn * 32;
    const u16* g2 = Cn + (long)tn * 32;
    u16* dA = As + sl * 4096;
    u16* d1 = B1s + sl * 4096;
    u16* d2 = B2s + sl * 4096;
    async16(ga + ao0, dA + c0 * 8);
    async16(ga + ao1, dA + c1 * 8);
    async16(g1 + bo0, d1 + c0 * 8);
    async16(g1 + bo1, d1 + c1 * 8);
    async16(g2 + bo0, d2 + c0 * 8);
    async16(g2 + bo1, d2 + c1 * 8);
    if (++tn == ksteps) {
      tn = 0; ++pn;
      if (pn == 1) { An = Aa1; Bn = Ba1; Cn = Ca1; }
      else if (pn == 2) { An = Aa2; Bn = Ba2; Cn = Ca2; }
    }
  };

  issue(0);
  issue(1);
  int slot = 0;
  for (int i = 0; i < total; ++i) {
    if (i + 1 < total) asm volatile("s_waitcnt vmcnt(6)" ::: "memory");
    else               asm volatile("s_waitcnt vmcnt(0)" ::: "memory");
    __builtin_amdgcn_sched_barrier(0);
    __builtin_amdgcn_s_barrier();
    __builtin_amdgcn_sched_barrier(0);
    if (i + 2 < total) {
      int s2 = slot + 2; if (s2 >= 3) s2 -= 3;
      issue(s2);
    }
    const u16* Sa = As + slot * 4096;
    const u16* S1 = B1s + slot * 4096;
    const u16* S2 = B2s + slot * 4096;
    bf16x8 af[4], b1v[4], b2v[4];
#pragma unroll
    for (int k = 0; k < 4; ++k) af[k] = *(const bf16x8*)(Sa + aoffs[k]);
#pragma unroll
    for (int k = 0; k < 4; ++k) b1v[k] = *(const bf16x8*)(S1 + boffs[k]);
#pragma unroll
    for (int k = 0; k < 4; ++k) b2v[k] = *(const bf16x8*)(S2 + boffs[k]);
#pragma unroll
    for (int mi = 0; mi < 4; ++mi)
#pragma unroll
      for (int nj = 0; nj < 4; ++nj)
        a1[mi][nj] = __builtin_amdgcn_mfma_f32_16x16x32_bf16(
            af[mi], b1v[nj], a1[mi][nj], 0, 0, 0);
#pragma unroll
    for (int mi = 0; mi < 4; ++mi)
#pragma unroll
      for (int nj = 0; nj < 4; ++nj)
        a2[mi][nj] = __builtin_amdgcn_mfma_f32_16x16x32_bf16(
            af[mi], b2v[nj], a2[mi][nj], 0, 0, 0);
    if (++slot == 3) slot = 0;
  }
}

#define GEMM_EPI_IDX                                                    \
  const int lane = threadIdx.x & 63, wv = threadIdx.x >> 6;             \
  const int wr = (wv >> 1) * 64, wc = (wv & 1) * 64;                    \
  const int mcol = lane & 15, q = lane >> 4;                            \
  const int gm0 = by * 128, gn0 = bx * 128;

// fa1+fa2 fused, 3-pass dual-B.
__global__ __launch_bounds__(256) void k_gemm_fa12(const u16* Ah, const u16* Al,
    const u16* W1h, const u16* W1l, const u16* W2h, const u16* W2l,
    const float* bias, u16* Chi, u16* Clo) {
  __shared__ __align__(16) u16 As[12288], B1s[12288], B2s[12288];
  int bx, by; swz_xy(bx, by);
  const size_t arow = (size_t)by * 128 * 1280;
  const size_t wrow = (size_t)bx * 128 * 640;
  const u16* Aph[3]  = {Ah + arow, Al + arow, Ah + arow};
  const u16* B1ph[3] = {W1h + wrow, W1h + wrow, W1l + wrow};
  const u16* B2ph[3] = {W2h + wrow, W2h + wrow, W2l + wrow};
  f32x4 a1[4][4] = {}, a2[4][4] = {};
  gemm_core2(Aph, B1ph, B2ph, 1280, 640, 20, As, B1s, B2s, a1, a2);
  GEMM_EPI_IDX
#pragma unroll
  for (int mi = 0; mi < 4; ++mi)
#pragma unroll
    for (int r = 0; r < 4; ++r) {
      int grow = gm0 + wr + mi * 16 + q * 4 + r;
#pragma unroll
      for (int ni = 0; ni < 4; ++ni) {
        int gcol = gn0 + wc + ni * 16 + mcol;
        float v1 = fmaxf(a1[mi][ni][r] + bias[gcol], 0.f);
        float v2 = fmaxf(a2[mi][ni][r] + bias[640 + gcol], 0.f);
        float y = v1 * v2;
        u16 h = f2bf(y);
        Chi[(size_t)grow * 1280 + 640 + gcol] = h;
        Clo[(size_t)grow * 1280 + 640 + gcol] = f2bf(y - bf2f(h));
      }
    }
}

// lp: [512,2048] @ [2560,2048]^T, fused 3-product, relu -> f32 [512,2560]
__global__ __launch_bounds__(256) void k_gemm_lp(const u16* Ah, const u16* Al,
    const u16* Wh, const u16* Wl, const float* bias, float* outp) {
  __shared__ __align__(16) u16 S[32768];
  int bx, by; swz_xy(bx, by);
  const size_t arow = (size_t)by * 128 * 2048;
  const size_t wrow = (size_t)bx * 128 * 2048;
  f32x4 acc[4][4] = {};
  gemm_fused3(Ah + arow, Al + arow, Wh + wrow, Wl + wrow, 2048, 2048, 64, S,
              acc);
  GEMM_EPI_IDX
#pragma unroll
  for (int mi = 0; mi < 4; ++mi)
#pragma unroll
    for (int r = 0; r < 4; ++r) {
      int grow = gm0 + wr + mi * 16 + q * 4 + r;
#pragma unroll
      for (int ni = 0; ni < 4; ++ni) {
        int gcol = gn0 + wc + ni * 16 + mcol;
        outp[(size_t)grow * 2560 + gcol] = fmaxf(acc[mi][ni][r] + bias[gcol], 0.f);
      }
    }
}

// ================== fa3+fa4: 256^2 8-wave 8-phase core ==================
// (R6 structure, proven 41.6% MfmaUtil.)
__global__ __launch_bounds__(512, 2) void k_gemm_fa34(const u16* Ah,
    const u16* Al, const u16* Wh, const u16* Wl, const float* b34,
    const float* lp_o, u16* fa3h, u16* fa3l, u16* fa4h, u16* fa4l, int r0) {
  __shared__ __align__(16) u16 S[2][4][8192];  // [buf][Ah,Al,Bh,Bl][256*32]
  int bx, by; swz_xy(bx, by);  // grid (10, RN/256)
  const int tid = threadIdx.x;
  const int lane = tid & 63, wv = tid >> 6;
  const int wm = wv >> 2, wn = wv & 3;
  const int mrow = lane & 15, q = lane >> 4;

  const size_t arow = (size_t)by * 256 * 1280;
  const size_t wrow = (size_t)bx * 256 * 1280;
  const u16* mats[4] = {Ah + arow, Al + arow, Wh + wrow, Wl + wrow};

  long soff[2];
#pragma unroll
  for (int j = 0; j < 2; ++j) {
    const int c = j * 512 + tid;
    soff[j] = (long)(c >> 2) * 1280 + ((c & 3) ^ ((c >> 3) & 3)) * 8;
  }
  int aoffs[8], boffs[4];
#pragma unroll
  for (int k = 0; k < 8; ++k) {
    const int r = wm * 128 + k * 16 + mrow;
    aoffs[k] = r * 32 + ((q ^ ((r >> 1) & 3)) << 3);
  }
#pragma unroll
  for (int k = 0; k < 4; ++k) {
    const int r = wn * 64 + k * 16 + mrow;
    boffs[k] = r * 32 + ((q ^ ((r >> 1) & 3)) << 3);
  }

  f32x4 acc[8][4] = {};
  const int ks = 40;  // K=1280 / 32

#pragma unroll
  for (int m = 0; m < 4; ++m) {
    async16(mats[m] + soff[0], &S[0][m][tid * 8]);
    async16(mats[m] + soff[1], &S[0][m][(512 + tid) * 8]);
  }
  asm volatile("s_waitcnt vmcnt(0)" ::: "memory");
  __builtin_amdgcn_sched_barrier(0);
  __builtin_amdgcn_s_barrier();

  for (int t = 0; t < ks; ++t) {
    const int cur = t & 1;
    const long ta = (long)(t + 1) * 32;
    const bool more = (t + 1 < ks);
    bf16x8 bh[4], bl[4];
#pragma unroll
    for (int p = 0; p < 8; ++p) {
      if (p == 0) {
#pragma unroll
        for (int k = 0; k < 4; ++k) {
          bh[k] = *(const bf16x8*)(&S[cur][2][0] + boffs[k]);
          bl[k] = *(const bf16x8*)(&S[cur][3][0] + boffs[k]);
        }
      }
      bf16x8 ah = *(const bf16x8*)(&S[cur][0][0] + aoffs[p]);
      bf16x8 al = *(const bf16x8*)(&S[cur][1][0] + aoffs[p]);
      if (p < 4 && more) {
        async16(mats[p] + ta + soff[0], &S[cur ^ 1][p][tid * 8]);
        async16(mats[p] + ta + soff[1], &S[cur ^ 1][p][(512 + tid) * 8]);
      }
      __builtin_amdgcn_s_barrier();
      asm volatile("s_waitcnt lgkmcnt(0)" ::: "memory");
      __builtin_amdgcn_sched_barrier(0);
      __builtin_amdgcn_s_setprio(1);
#pragma unroll
      for (int j = 0; j < 4; ++j)
        acc[p][j] = __builtin_amdgcn_mfma_f32_16x16x32_bf16(ah, bh[j],
                                                            acc[p][j], 0, 0, 0);
#pragma unroll
      for (int j = 0; j < 4; ++j)
        acc[p][j] = __builtin_amdgcn_mfma_f32_16x16x32_bf16(al, bh[j],
                                                            acc[p][j], 0, 0, 0);
#pragma unroll
      for (int j = 0; j < 4; ++j)
        acc[p][j] = __builtin_amdgcn_mfma_f32_16x16x32_bf16(ah, bl[j],
                                                            acc[p][j], 0, 0, 0);
      __builtin_amdgcn_s_setprio(0);
      __builtin_amdgcn_s_barrier();
    }
    if (more) {
      asm volatile("s_waitcnt vmcnt(0)" ::: "memory");
      __builtin_amdgcn_sched_barrier(0);
      __builtin_amdgcn_s_barrier();
    }
  }

  const int gm0 = by * 256, gn0 = bx * 256;
  const int seg = (gn0 >= 1280);
  u16* dsth = seg ? fa4h : fa3h;
  u16* dstl = seg ? fa4l : fa3l;
#pragma unroll
  for (int p = 0; p < 8; ++p)
#pragma unroll
    for (int r = 0; r < 4; ++r) {
      const int grow = gm0 + wm * 128 + p * 16 + q * 4 + r;
      const int b = (r0 + grow) / 50;
      const float* lpb = lp_o + (size_t)b * 2560;
#pragma unroll
      for (int j = 0; j < 4; ++j) {
        const int gcol = gn0 + wn * 64 + j * 16 + mrow;
        const int c = gcol - seg * 1280;
        float v = fmaxf(acc[p][j][r] + b34[gcol], 0.f);
        if (!seg) v *= lpb[c];
        if (c < 1216) {
          u16 h = f2bf(v);
          dsth[(size_t)grow * 1216 + c] = h;
          dstl[(size_t)grow * 1216 + c] = f2bf(v - bf2f(h));
        }
      }
    }
}

// fa5: 1-pass 128^2 core.
__global__ __launch_bounds__(256) void k_gemm_fa5(const u16* Ah,
    const u16* W5h, const float* b5, const float* lp_o, u16* fa5o, int r0) {
  __shared__ __align__(16) u16 S[32768];
  int bx, by; swz_xy(bx, by);  // grid (10, RN/128)
  const size_t arow = (size_t)by * 128 * 1280;
  const size_t wrow = (size_t)bx * 128 * 1280;
  f32x4 acc[4][4] = {};
  gemm_core1(Ah + arow, W5h + wrow, 1280, 1280, 40, S, S + 16384, acc);
  GEMM_EPI_IDX
#pragma unroll
  for (int mi = 0; mi < 4; ++mi)
#pragma unroll
    for (int r = 0; r < 4; ++r) {
      int grow = gm0 + wr + mi * 16 + q * 4 + r;
      int b = (r0 + grow) / 50;
      const float* lpb = lp_o + (size_t)b * 2560 + 1280;
#pragma unroll
      for (int ni = 0; ni < 4; ++ni) {
        int gcol = gn0 + wc + ni * 16 + mcol;
        float v = fmaxf(acc[mi][ni][r] + b5[gcol], 0.f) * lpb[gcol];
        if (gcol < 1216) fa5o[(size_t)grow * 1216 + gcol] = f2bf(v);
      }
    }
}

// out FC, 1-pass: messages = relu(msg@outw^T+b), masked, -> d_out cols 300..599
__global__ __launch_bounds__(256) void k_gemm_out(const u16* A, const u16* Wh,
    const float* bias, const int* mask_s, float* outp, int r0) {
  __shared__ __align__(16) u16 S[32768];
  int bx, by; swz_xy(bx, by);
  const size_t arow = (size_t)by * 128 * 1216;
  const size_t wrow = (size_t)bx * 128 * 1216;
  f32x4 acc[4][4] = {};
  gemm_core1(A + arow, Wh + wrow, 1216, 1216, 38, S, S + 16384, acc);
  GEMM_EPI_IDX
#pragma unroll
  for (int mi = 0; mi < 4; ++mi)
#pragma unroll
    for (int r = 0; r < 4; ++r) {
      int grow = r0 + gm0 + wr + mi * 16 + q * 4 + r;  // global row
      int b = grow / 50;
      int n = grow - b * 50;
      float keep = (n < mask_s[b]) ? 1.f : 0.f;
#pragma unroll
      for (int ni = 0; ni < 4; ++ni) {
        int gcol = gn0 + wc + ni * 16 + mcol;
        float v = fmaxf(acc[mi][ni][r] + bias[gcol], 0.f) * keep;
        if (gcol < 300) outp[(size_t)grow * 600 + 300 + gcol] = v;
      }
    }
}

// ============================ attention ============================
// R8: 512 threads / 8 waves per block (2 waves/SIMD instead of 1).
// Phase 1: waves 0-3 stage A(fa4), waves 4-7 stage B(fa3), 1 async16 per
// thread per stage; MFMA split 8 ways (wave = row-tile x col-pair, acc[2]).
// Counted vmcnt scaled to 1 load/wave/stage. Softmax rows striped over 8
// waves. Phase 3: 1 async16/thread/stage, same 8-way MFMA split.
__global__ __launch_bounds__(512) void k_attn(const u16* fa3h, const u16* fa3l,
    const u16* fa4h, const u16* fa4l, const u16* fa5o, const int* mask_s,
    float* adj_out, u16* msg, int b0) {
  __shared__ __align__(16) u16 stg[32768];  // 8 slots x 8KB
  __shared__ float Ssc[64 * 64];
  const int bl = blockIdx.x;
  const int bg = b0 + bl;
  const int tid = threadIdx.x, lane = tid & 63, wv = tid >> 6;
  const int rt = wv >> 1;   // row-tile 0..3
  const int cp = wv & 1;    // col-pair 0..1 -> col-tiles {2cp, 2cp+1}
  const int mrow = lane & 15, q = lane >> 4;
  const size_t base = (size_t)bl * 50 * 1216;

  // ---- phase 1: logits (3 passes flattened: h*h, l*h, h*l) ----
  {
    const int idx = tid & 255;
    const int half = tid >> 8;  // 0: A (fa4), 1: B (fa3)
    const int srow = idx >> 2;
    const int srcRow = srow < 50 ? srow : 49;
    const size_t gsoff = base + (size_t)srcRow * 1216 +
                         (size_t)(((idx & 3) ^ ((idx >> 3) & 3)) * 8);
    auto issueP1 = [&](int sl, int s) {
      const int p = (s >= 76) ? 2 : (s >= 38 ? 1 : 0);
      const int t = s - p * 38;
      const u16* src;
      if (half == 0) src = (p == 1) ? fa4l : fa4h;
      else           src = (p == 2) ? fa3l : fa3h;
      async16(src + gsoff + (size_t)t * 32,
              stg + sl * 4096 + half * 2048 + idx * 8);
    };
    const int ra = rt * 16 + mrow;
    const int aoff = ra * 32 + ((q ^ ((ra >> 1) & 3)) << 3);
    int boff[2];
#pragma unroll
    for (int j = 0; j < 2; ++j) {
      const int rb = (2 * cp + j) * 16 + mrow;
      boff[j] = rb * 32 + ((q ^ ((rb >> 1) & 3)) << 3);
    }
    for (int j = 0; j < 7; ++j) issueP1(j, j);
    f32x4 acc[2] = {};
    int cs = 0, is = 7;
    for (int i = 0; i < 114; ++i) {
      const int rem = 113 - i;  // 1 load/wave/stage, 7 issued ahead
      if (rem >= 6)      asm volatile("s_waitcnt vmcnt(6)" ::: "memory");
      else if (rem == 5) asm volatile("s_waitcnt vmcnt(5)" ::: "memory");
      else if (rem == 4) asm volatile("s_waitcnt vmcnt(4)" ::: "memory");
      else if (rem == 3) asm volatile("s_waitcnt vmcnt(3)" ::: "memory");
      else if (rem == 2) asm volatile("s_waitcnt vmcnt(2)" ::: "memory");
      else if (rem == 1) asm volatile("s_waitcnt vmcnt(1)" ::: "memory");
      else               asm volatile("s_waitcnt vmcnt(0)" ::: "memory");
      __builtin_amdgcn_sched_barrier(0);
      __builtin_amdgcn_s_barrier();
      __builtin_amdgcn_sched_barrier(0);
      if (i + 7 < 114) { issueP1(is, i + 7); if (++is == 8) is = 0; }
      const u16* d = stg + cs * 4096;
      if (++cs == 8) cs = 0;
      bf16x8 af = *(const bf16x8*)(d + aoff);
#pragma unroll
      for (int j = 0; j < 2; ++j) {
        bf16x8 bv = *(const bf16x8*)(d + 2048 + boff[j]);
        acc[j] =
            __builtin_amdgcn_mfma_f32_16x16x32_bf16(af, bv, acc[j], 0, 0, 0);
      }
    }
#pragma unroll
    for (int j = 0; j < 2; ++j)
#pragma unroll
      for (int r = 0; r < 4; ++r)
        Ssc[(rt * 16 + q * 4 + r) * 64 + (2 * cp + j) * 16 + mrow] = acc[j][r];
  }
  __syncthreads();

  // ---- phase-3 staging geometry (needed for early prologue) ----
  const int m0 = tid >> 3, d0 = (tid & 7) * 8;  // m 0..63, full 64x64 tile
  const size_t g0 = base + (size_t)(m0 < 50 ? m0 : 49) * 1216 + d0;
  auto issueP3 = [&](int sl, int s) {
    async16(fa5o + g0 + (size_t)s * 64, stg + sl * 4096 + tid * 8);
  };
  // prologue: issue 7 stages now; phase-2 softmax hides the latency
  for (int j = 0; j < 7; ++j) issueP3(j, j);

  // ---- phase 2: mask + softmax, write adj (rows striped over 8 waves) ----
  {
    const int mk = mask_s[bg];
    for (int n = wv; n < 50; n += 8) {
      int mm = lane;
      float v = -__builtin_inff();
      if (mm < 50) {
        int mx2 = n > mm ? n : mm;
        bool valid = (mx2 < mk) || (n >= mk);
        if (mm == n) valid = false;
        if (n == 0 && mm == 0 && mk == 1) valid = true;
        if (valid) v = Ssc[n * 64 + mm];
      }
      float mx = v;
      for (int o = 32; o > 0; o >>= 1) mx = fmaxf(mx, __shfl_down(mx, o));
      mx = __shfl(mx, 0);
      float e = __expf(v - mx);
      float sm = e;
      for (int o = 32; o > 0; o >>= 1) sm += __shfl_down(sm, o);
      sm = __shfl(sm, 0);
      float pv = e / sm;
      if (mm < 50) {
        adj_out[((size_t)bg * 50 + n) * 50 + mm] = pv;
        Ssc[n * 64 + mm] = pv;
      } else {
        Ssc[n * 64 + mm] = 0.f;
      }
    }
  }
  __syncthreads();

  // ---- phase 3: msg[n][d] = sum_m adj[n][m] * fa5o[m][d] ----
  {
    int cs = 0, is = 7;
    for (int dt = 0; dt < 19; ++dt) {
      const int rem = 18 - dt;
      if (rem >= 6)      asm volatile("s_waitcnt vmcnt(6)" ::: "memory");
      else if (rem == 5) asm volatile("s_waitcnt vmcnt(5)" ::: "memory");
      else if (rem == 4) asm volatile("s_waitcnt vmcnt(4)" ::: "memory");
      else if (rem == 3) asm volatile("s_waitcnt vmcnt(3)" ::: "memory");
      else if (rem == 2) asm volatile("s_waitcnt vmcnt(2)" ::: "memory");
      else if (rem == 1) asm volatile("s_waitcnt vmcnt(1)" ::: "memory");
      else               asm volatile("s_waitcnt vmcnt(0)" ::: "memory");
      __builtin_amdgcn_sched_barrier(0);
      __builtin_amdgcn_s_barrier();
      __builtin_amdgcn_sched_barrier(0);
      if (dt + 7 < 19) { issueP3(is, dt + 7); if (++is == 8) is = 0; }
      const u16* d = stg + cs * 4096;
      if (++cs == 8) cs = 0;
      f32x4 a3[2] = {};
#pragma unroll
      for (int ks = 0; ks < 2; ++ks) {
        bf16x8 af;
#pragma unroll
        for (int j = 0; j < 8; ++j)
          af[j] = (__bf16)Ssc[(rt * 16 + mrow) * 64 + ks * 32 + q * 8 + j];
#pragma unroll
        for (int jj = 0; jj < 2; ++jj) {
          const int ni = 2 * cp + jj;
          bf16x8 bv;
#pragma unroll
          for (int j = 0; j < 8; ++j)
            bv[j] = *(const __bf16*)(d + (ks * 32 + q * 8 + j) * 64 + ni * 16 + mrow);
          a3[jj] = __builtin_amdgcn_mfma_f32_16x16x32_bf16(af, bv, a3[jj], 0, 0, 0);
        }
      }
#pragma unroll
      for (int jj = 0; jj < 2; ++jj)
#pragma unroll
        for (int r = 0; r < 4; ++r) {
          int n = rt * 16 + q * 4 + r;
          if (n < 50)
            msg[((size_t)bl * 50 + n) * 1216 + dt * 64 + (2 * cp + jj) * 16 + mrow] =
                f2bf(a3[jj][r]);
        }
    }
  }
}

// ============================ host ============================
extern "C" void kernel_launch(void* const* d_in, const int* in_sizes, int n_in,
                              void* d_out_, int out_size, void* d_ws,
                              size_t ws_size, hipStream_t stream) {
  (void)in_sizes; (void)n_in; (void)out_size;
  const float* l_in = (const float*)d_in[0];
  const float* s_in = (const float*)d_in[1];
  const float* ps   = (const float*)d_in[2];
  const int*   msk  = (const int*)d_in[3];
  const float* bbw  = (const float*)d_in[4];
  const float* bbb  = (const float*)d_in[5];
  const float* fa1w = (const float*)d_in[6];
  const float* fa1b = (const float*)d_in[7];
  const float* fa2w = (const float*)d_in[8];
  const float* fa2b = (const float*)d_in[9];
  const float* fa3w = (const float*)d_in[10];
  const float* fa3b = (const float*)d_in[11];
  const float* fa4w = (const float*)d_in[12];
  const float* fa4b = (const float*)d_in[13];
  const float* fa5w = (const float*)d_in[14];
  const float* fa5b = (const float*)d_in[15];
  const float* lp1w = (const float*)d_in[16];
  const float* lp1b = (const float*)d_in[17];
  const float* lp2w = (const float*)d_in[18];
  const float* lp2b = (const float*)d_in[19];
  const float* outw = (const float*)d_in[20];
  const float* outb = (const float*)d_in[21];
  float* outp = (float*)d_out_;

  char* wsb = (char*)d_ws;
  size_t off = 0;
  auto alloc = [&](size_t bytes) -> char* {
    char* p = wsb + off;
    off = (off + bytes + 255) & ~(size_t)255;
    return p;
  };
  // ---- persistent (~31 MB) ----
  u16*   l_hi   = (u16*)alloc(512ull * 2048 * 2);
  u16*   l_lo   = (u16*)alloc(512ull * 2048 * 2);
  u16*   Wout   = (u16*)alloc(384ull * 1216 * 2);
  float* b_fa12 = (float*)alloc(1280 * 4);
  float* b_fa34 = (float*)alloc(2560 * 4);
  float* b_fa5  = (float*)alloc(1280 * 4);
  float* b_lp   = (float*)alloc(2560 * 4);
  float* b_out  = (float*)alloc(384 * 4);
  float* lp_o   = (float*)alloc(512ull * 2560 * 4);
  // weight slab, time-shared: lp weights -> fa* weights (stream-ordered).
  u16*   slab   = (u16*)alloc(10485760ull * 2);
  u16* Wlph   = slab;                  // 2560x2048
  u16* Wlpl   = slab + 5242880;        // 2560x2048
  u16* Wfa1h  = slab;                  // 640x640
  u16* Wfa1l  = slab + 409600;
  u16* Wfa2h  = slab + 819200;
  u16* Wfa2l  = slab + 1228800;
  u16* Wfa34h = slab + 1638400;        // 2560x1280
  u16* Wfa34l = slab + 4915200;        // 2560x1280
  u16* Wfa5h  = slab + 8192000;        // 1280x1280

  // chunk rows RN (must be multiple of 256 for the fa34 grid)
  size_t ws_eff = ws_size ? ws_size : (size_t)512 * 1024 * 1024;
  long RN = 6400;
  const long opts[3] = {25600, 12800, 6400};
  for (int i = 0; i < 3; ++i) {
    size_t need = off + (size_t)17280 * opts[i] + 8 * 256;
    if (need <= ws_eff) { RN = opts[i]; break; }
  }
  u16*  Chi  = (u16*)alloc((size_t)RN * 1280 * 2);
  u16*  Clo  = (u16*)alloc((size_t)RN * 1280 * 2);
  u16*  fa5o = (u16*)alloc((size_t)RN * 1216 * 2);
  u16*  fa3h = (u16*)alloc((size_t)RN * 1216 * 2);
  u16*  fa3l = (u16*)alloc((size_t)RN * 1216 * 2);
  u16*  fa4h = (u16*)alloc((size_t)RN * 1216 * 2);
  u16*  fa4l = (u16*)alloc((size_t)RN * 1216 * 2);
  u16*  msg  = Chi;  // combined dead after fa34/fa5; reuse for messages_in
  float* adj_o = outp + 15360000;

  dim3 T(256);
  // biases (padded)
  k_pack_bias<<<dim3(3), T, 0, stream>>>(fa1b, 600, b_fa12, 640);
  k_pack_bias<<<dim3(3), T, 0, stream>>>(fa2b, 600, b_fa12 + 640, 640);
  k_pack_bias<<<dim3(5), T, 0, stream>>>(fa3b, 1200, b_fa34, 1280);
  k_pack_bias<<<dim3(5), T, 0, stream>>>(fa4b, 1200, b_fa34 + 1280, 1280);
  k_pack_bias<<<dim3(5), T, 0, stream>>>(fa5b, 1200, b_fa5, 1280);
  k_pack_bias<<<dim3(5), T, 0, stream>>>(lp1b, 1200, b_lp, 1280);
  k_pack_bias<<<dim3(5), T, 0, stream>>>(lp2b, 1200, b_lp + 1280, 1280);
  k_pack_bias<<<dim3(2), T, 0, stream>>>(outb, 300, b_out, 384);

  auto packw = [&](const float* src, int n, int k, u16* hi, u16* lo, int KP,
                   long total, int gap) {
    k_pack_w<<<dim3((unsigned)((total + 255) / 256)), T, 0, stream>>>(
        src, n, k, hi, lo, KP, total, gap);
  };
  // static packs
  packw(l_in, 512, 2048, l_hi, l_lo, 2048, 512L * 2048, 0);
  packw(outw, 300, 1200, Wout, nullptr, 1216, 384L * 1216, 0);

  // lp stage
  packw(lp1w, 1200, 2048, Wlph, Wlpl, 2048, 1280L * 2048, 0);
  packw(lp2w, 1200, 2048, Wlph + 1280 * 2048, Wlpl + 1280 * 2048, 2048,
        1280L * 2048, 0);
  k_gemm_lp<<<dim3(20, 4), T, 0, stream>>>(l_hi, l_lo, Wlph, Wlpl, b_lp, lp_o);

  // fa weights into slab (lp weights dead after k_gemm_lp)
  packw(fa1w, 600, 600, Wfa1h, Wfa1l, 640, 640L * 640, 0);
  packw(fa2w, 600, 600, Wfa2h, Wfa2l, 640, 640L * 640, 0);
  packw(fa3w, 1200, 1200, Wfa34h, Wfa34l, 1280, 1280L * 1280, 1);
  packw(fa4w, 1200, 1200, Wfa34h + 1638400, Wfa34l + 1638400, 1280,
        1280L * 1280, 1);
  packw(fa5w, 1200, 1200, Wfa5h, nullptr, 1280, 1280L * 1280, 1);

  // ---- chunk loop ----
  const int nch = (int)(25600 / RN);
  const unsigned gy = (unsigned)(RN / 128);
  for (int c = 0; c < nch; ++c) {
    const int r0 = (int)(c * RN);
    const int b0 = r0 / 50;
    k_bb<<<dim3((unsigned)RN), T, 0, stream>>>(s_in + (size_t)r0 * 300,
                                               ps + (size_t)r0 * 4, bbw, bbb,
                                               msk, Chi, Clo, outp, r0);
    k_gemm_fa12<<<dim3(5, gy), T, 0, stream>>>(Chi, Clo, Wfa1h, Wfa1l, Wfa2h,
                                               Wfa2l, b_fa12, Chi, Clo);
    k_gemm_fa34<<<dim3(10, (unsigned)(RN / 256)), dim3(512), 0, stream>>>(
        Chi, Clo, Wfa34h, Wfa34l, b_fa34, lp_o, fa3h, fa3l, fa4h, fa4l, r0);
    k_gemm_fa5<<<dim3(10, gy), T, 0, stream>>>(Chi, Wfa5h, b_fa5, lp_o, fa5o,
                                               r0);
    k_attn<<<dim3((unsigned)(RN / 50)), dim3(512), 0, stream>>>(
        fa3h, fa3l, fa4h, fa4l, fa5o, msk, adj_o, msg, b0);
    k_gemm_out<<<dim3(3, gy), T, 0, stream>>>(msg, Wout, b_out, msk, outp, r0);
  }
}

// Round 9
// 1388.743 us; speedup vs baseline: 1.0942x; 1.0942x over previous
//
#include <hip/hip_runtime.h>
#include <stdint.h>

typedef unsigned short u16;
typedef unsigned int u32;
typedef __attribute__((ext_vector_type(8))) __bf16 bf16x8;
typedef __attribute__((ext_vector_type(4))) float f32x4;

#define DEVINL static __device__ __forceinline__

// round-to-nearest-even f32 -> bf16
DEVINL u16 f2bf(float x) {
  u32 u = __float_as_uint(x);
  return (u16)((u + (((u >> 16) & 1u) + 0x7fffu)) >> 16);
}
DEVINL float bf2f(u16 h) { return __uint_as_float(((u32)h) << 16); }

// async global->LDS, 16B per lane. HW semantics: wave-uniform base + lane*16.
DEVINL void async16(const void* g, void* l) {
  void* g2 = const_cast<void*>(g);
  __builtin_amdgcn_global_load_lds((__attribute__((address_space(1))) void*)g2,
                                   (__attribute__((address_space(3))) void*)l,
                                   16, 0, 0);
}

// bijective XCD-aware block swizzle (m204 form).
DEVINL void swz_xy(int& bx, int& by) {
  const int gx = (int)gridDim.x;
  const int nwg = gx * (int)gridDim.y;
  const int bid = (int)blockIdx.y * gx + (int)blockIdx.x;
  const int q = nwg >> 3, r = nwg & 7, x = bid & 7, t = bid >> 3;
  const int s = (x < r ? x * (q + 1) : r * (q + 1) + (x - r) * q) + t;
  bx = s % gx;
  by = s / gx;
}

// LDS bank-conflict swizzle (both-sides rule): physical 16B slot =
// logical slot ^ ((row>>1)&3). Staging keeps LDS dest linear and permutes
// the GLOBAL source slot; fragment reads apply the same XOR.

// ============================ pack kernels ============================
__global__ void k_pack_w(const float* src, int n, int k, u16* hi, u16* lo,
                         int KP, long total, int gap) {
  long i = (long)blockIdx.x * 256 + threadIdx.x;
  if (i >= total) return;
  int r = (int)(i / KP);
  int c = (int)(i - (long)r * KP);
  int sc = c;
  bool ok = (r < n);
  if (gap) {
    if (c >= 600 && c < 640) ok = false;
    else if (c >= 640) sc = c - 40;
  }
  if (sc >= k) ok = false;
  float x = ok ? src[(size_t)r * k + sc] : 0.f;
  u16 h = f2bf(x);
  hi[i] = h;
  if (lo) lo[i] = f2bf(x - bf2f(h));
}

__global__ void k_pack_bias(const float* src, int n, float* dst, int NP) {
  int i = blockIdx.x * 256 + threadIdx.x;
  if (i < NP) dst[i] = (i < n) ? src[i] : 0.f;
}

// ==== bb_process + concat(s, bb) -> combined[:, 0:640]; also writes ====
// ==== d_out cols 0..299 = s * mask                                   ====
__global__ void k_bb(const float* s_c, const float* ps_c, const float* bb_w,
                     const float* bb_b, const int* mask_s, u16* Chi, u16* Clo,
                     float* outp, int r0) {
  int rn = blockIdx.x;
  int grow = r0 + rn;
  int b = grow / 50;
  int n = grow - b * 50;
  float keep = (n < mask_s[b]) ? 1.f : 0.f;
  const float* p = ps_c + (size_t)rn * 4;
  float p0 = p[0], p1 = p[1], p2 = p[2], p3 = p[3];
  float sz0 = p2 - p0, sz1 = p3 - p1;
  float bin[10];
  bin[0] = p0; bin[1] = p1; bin[2] = p2; bin[3] = p3;
  bin[4] = sz0; bin[5] = sz1;
  bin[6] = p0 + 0.5f * sz0; bin[7] = p1 + 0.5f * sz1;
  bin[8] = sz0 * sz1; bin[9] = sz0 / (sz1 + 1e-14f);
  for (int c = threadIdx.x; c < 640; c += 256) {
    float x = 0.f;
    if (c < 300) {
      x = s_c[(size_t)rn * 300 + c];
      outp[(size_t)grow * 600 + c] = keep * x;
    } else if (c < 600) {
      int j = c - 300;
      float a = bb_b[j];
      const float* wr = bb_w + j * 10;
#pragma unroll
      for (int kk = 0; kk < 10; ++kk) a += bin[kk] * wr[kk];
      x = fmaxf(a, 0.f);
    }
    u16 h = f2bf(x);
    Chi[(size_t)rn * 1280 + c] = h;
    Clo[(size_t)rn * 1280 + c] = f2bf(x - bf2f(h));
  }
}

// ============================ GEMM cores ============================

// Fused 3-product core (lp only): acc += Ah*Bh + Al*Bh + Ah*Bl.
// Two 16KB half-phases per K-step over 4 half-buffers (64KB, 2 blocks/CU),
// counted vmcnt(8).
DEVINL void gemm_fused3(const u16* Ahp, const u16* Alp, const u16* Bhp,
                        const u16* Blp, int lda, int ldw, int ksteps,
                        u16* S, f32x4 (&acc)[4][4]) {
  const int tid = threadIdx.x;
  const int lane = tid & 63;
  const int wv = tid >> 6;
  const int wr = (wv >> 1) * 64;
  const int wc = (wv & 1) * 64;
  const int mrow = lane & 15;
  const int q = lane >> 4;

  const int c0 = tid, c1 = tid + 256;
  const int p0 = ((c0 & 3) ^ ((c0 >> 3) & 3)) * 8;  // swizzled src slot
  const int p1 = ((c1 & 3) ^ ((c1 >> 3) & 3)) * 8;
  const long ao0 = (long)(c0 >> 2) * lda + p0;
  const long ao1 = (long)(c1 >> 2) * lda + p1;
  const long bo0 = (long)(c0 >> 2) * ldw + p0;
  const long bo1 = (long)(c1 >> 2) * ldw + p1;

  int aoffs[4], boffs[4];
#pragma unroll
  for (int k = 0; k < 4; ++k) {
    const int ra = wr + mrow + 16 * k;
    const int rb = wc + mrow + 16 * k;
    aoffs[k] = ra * 32 + ((q ^ ((ra >> 1) & 3)) << 3);
    boffs[k] = rb * 32 + ((q ^ ((rb >> 1) & 3)) << 3);
  }

  auto issueF = [&](int ph) {
    const long ta = (long)(ph >> 1) * 32;
    const u16* sa = (ph & 1) ? Alp : Ahp;
    const u16* sb = (ph & 1) ? Blp : Bhp;
    u16* d = S + (ph & 3) * 8192;
    async16(sa + ta + ao0, d + c0 * 8);
    async16(sa + ta + ao1, d + c1 * 8);
    async16(sb + ta + bo0, d + 4096 + c0 * 8);
    async16(sb + ta + bo1, d + 4096 + c1 * 8);
  };

  const int total = 2 * ksteps;
  issueF(0); issueF(1); if (total > 2) issueF(2);
  bf16x8 ah[4], bh[4];
  for (int i = 0; i < ksteps; ++i) {
    {
      const int rem = total - 1 - 2 * i;
      if (rem >= 2)      asm volatile("s_waitcnt vmcnt(8)" ::: "memory");
      else               asm volatile("s_waitcnt vmcnt(4)" ::: "memory");
      __builtin_amdgcn_sched_barrier(0);
      __builtin_amdgcn_s_barrier();
      __builtin_amdgcn_sched_barrier(0);
      if (2 * i + 3 < total) issueF(2 * i + 3);
      const u16* hb = S + ((2 * i) & 3) * 8192;
#pragma unroll
      for (int k = 0; k < 4; ++k) {
        ah[k] = *(const bf16x8*)(hb + aoffs[k]);
        bh[k] = *(const bf16x8*)(hb + 4096 + boffs[k]);
      }
#pragma unroll
      for (int mi = 0; mi < 4; ++mi)
#pragma unroll
        for (int nj = 0; nj < 4; ++nj)
          acc[mi][nj] = __builtin_amdgcn_mfma_f32_16x16x32_bf16(
              ah[mi], bh[nj], acc[mi][nj], 0, 0, 0);
    }
    {
      const int rem = total - 2 - 2 * i;
      if (rem >= 2)      asm volatile("s_waitcnt vmcnt(8)" ::: "memory");
      else if (rem == 1) asm volatile("s_waitcnt vmcnt(4)" ::: "memory");
      else               asm volatile("s_waitcnt vmcnt(0)" ::: "memory");
      __builtin_amdgcn_sched_barrier(0);
      __builtin_amdgcn_s_barrier();
      __builtin_amdgcn_sched_barrier(0);
      if (2 * i + 4 < total) issueF(2 * i + 4);
      const u16* hb = S + ((2 * i + 1) & 3) * 8192;
      bf16x8 al[4], bl[4];
#pragma unroll
      for (int k = 0; k < 4; ++k) {
        al[k] = *(const bf16x8*)(hb + aoffs[k]);
        bl[k] = *(const bf16x8*)(hb + 4096 + boffs[k]);
      }
#pragma unroll
      for (int mi = 0; mi < 4; ++mi)
#pragma unroll
        for (int nj = 0; nj < 4; ++nj)
          acc[mi][nj] = __builtin_amdgcn_mfma_f32_16x16x32_bf16(
              al[mi], bh[nj], acc[mi][nj], 0, 0, 0);
#pragma unroll
      for (int mi = 0; mi < 4; ++mi)
#pragma unroll
        for (int nj = 0; nj < 4; ++nj)
          acc[mi][nj] = __builtin_amdgcn_mfma_f32_16x16x32_bf16(
              ah[mi], bl[nj], acc[mi][nj], 0, 0, 0);
    }
  }
}

// single-pass core (fa5, out): 4 slots (64KB), depth-3 counted vmcnt.
DEVINL void gemm_core1(const u16* Ab, const u16* Bb, int lda, int ldw,
                       int ksteps, u16* As, u16* Bs, f32x4 (&acc)[4][4]) {
  const int tid = threadIdx.x;
  const int lane = tid & 63;
  const int wv = tid >> 6;
  const int wr = (wv >> 1) * 64;
  const int wc = (wv & 1) * 64;
  const int mrow = lane & 15;
  const int q = lane >> 4;

  const int c0 = tid, c1 = tid + 256;
  const int p0 = ((c0 & 3) ^ ((c0 >> 3) & 3)) * 8;
  const int p1 = ((c1 & 3) ^ ((c1 >> 3) & 3)) * 8;
  const long ao0 = (long)(c0 >> 2) * lda + p0;
  const long ao1 = (long)(c1 >> 2) * lda + p1;
  const long bo0 = (long)(c0 >> 2) * ldw + p0;
  const long bo1 = (long)(c1 >> 2) * ldw + p1;

  int aoffs[4], boffs[4];
#pragma unroll
  for (int k = 0; k < 4; ++k) {
    const int ra = wr + mrow + 16 * k;
    const int rb = wc + mrow + 16 * k;
    aoffs[k] = ra * 32 + ((q ^ ((ra >> 1) & 3)) << 3);
    boffs[k] = rb * 32 + ((q ^ ((rb >> 1) & 3)) << 3);
  }

  auto issue = [&](int sl, int t) {
    const long ta = (long)t * 32;
    u16* dA = As + sl * 4096;
    u16* dB = Bs + sl * 4096;
    async16(Ab + ta + ao0, dA + c0 * 8);
    async16(Ab + ta + ao1, dA + c1 * 8);
    async16(Bb + ta + bo0, dB + c0 * 8);
    async16(Bb + ta + bo1, dB + c1 * 8);
  };

  const int npro = ksteps < 3 ? ksteps : 3;
  for (int j = 0; j < npro; ++j) issue(j, j);
  int cs = 0, is = 3;
  for (int i = 0; i < ksteps; ++i) {
    const int rem = ksteps - 1 - i;
    if (rem >= 2)      asm volatile("s_waitcnt vmcnt(8)" ::: "memory");
    else if (rem == 1) asm volatile("s_waitcnt vmcnt(4)" ::: "memory");
    else               asm volatile("s_waitcnt vmcnt(0)" ::: "memory");
    __builtin_amdgcn_sched_barrier(0);
    __builtin_amdgcn_s_barrier();
    __builtin_amdgcn_sched_barrier(0);
    if (i + 3 < ksteps) { issue(is, i + 3); is = (is + 1) & 3; }
    const u16* Sa = As + cs * 4096;
    const u16* Sb = Bs + cs * 4096;
    cs = (cs + 1) & 3;
    bf16x8 af[4], bv[4];
#pragma unroll
    for (int k = 0; k < 4; ++k) af[k] = *(const bf16x8*)(Sa + aoffs[k]);
#pragma unroll
    for (int k = 0; k < 4; ++k) bv[k] = *(const bf16x8*)(Sb + boffs[k]);
#pragma unroll
    for (int mi = 0; mi < 4; ++mi)
#pragma unroll
      for (int nj = 0; nj < 4; ++nj)
        acc[mi][nj] = __builtin_amdgcn_mfma_f32_16x16x32_bf16(
            af[mi], bv[nj], acc[mi][nj], 0, 0, 0);
  }
}

// dual-B variant (fa12): 3-pass, 3-slot depth-2 counted pipeline, swizzled.
DEVINL void gemm_core2(const u16* const Aph[3], const u16* const B1ph[3],
                       const u16* const B2ph[3], int lda, int ldw, int ksteps,
                       u16* As, u16* B1s, u16* B2s, f32x4 (&a1)[4][4],
                       f32x4 (&a2)[4][4]) {
  const int tid = threadIdx.x;
  const int lane = tid & 63;
  const int wv = tid >> 6;
  const int wr = (wv >> 1) * 64;
  const int wc = (wv & 1) * 64;
  const int mrow = lane & 15;
  const int q = lane >> 4;

  const int c0 = tid, c1 = tid + 256;
  const int p0 = ((c0 & 3) ^ ((c0 >> 3) & 3)) * 8;
  const int p1 = ((c1 & 3) ^ ((c1 >> 3) & 3)) * 8;
  const long ao0 = (long)(c0 >> 2) * lda + p0;
  const long ao1 = (long)(c1 >> 2) * lda + p1;
  const long bo0 = (long)(c0 >> 2) * ldw + p0;
  const long bo1 = (long)(c1 >> 2) * ldw + p1;

  int aoffs[4], boffs[4];
#pragma unroll
  for (int k = 0; k < 4; ++k) {
    const int ra = wr + mrow + 16 * k;
    const int rb = wc + mrow + 16 * k;
    aoffs[k] = ra * 32 + ((q ^ ((ra >> 1) & 3)) << 3);
    boffs[k] = rb * 32 + ((q ^ ((rb >> 1) & 3)) << 3);
  }

  const u16* Aa1 = Aph[1]; const u16* Ba1 = B1ph[1]; const u16* Ca1 = B2ph[1];
  const u16* Aa2 = Aph[2]; const u16* Ba2 = B1ph[2]; const u16* Ca2 = B2ph[2];
  const u16* An = Aph[0];  const u16* Bn = B1ph[0];  const u16* Cn = B2ph[0];
  int tn = 0, pn = 0;
  const int total = 3 * ksteps;

  auto issue = [&](int sl) {
    const u16* ga = An + (long)tn * 32;
    const u16* g1 = Bn + (long)tn * 32;
    const u16* g2 = Cn + (long)tn * 32;
    u16* dA = As + sl * 4096;
    u16* d1 = B1s + sl * 4096;
    u16* d2 = B2s + sl * 4096;
    async16(ga + ao0, dA + c0 * 8);
    async16(ga + ao1, dA + c1 * 8);
    async16(g1 + bo0, d1 + c0 * 8);
    async16(g1 + bo1, d1 + c1 * 8);
    async16(g2 + bo0, d2 + c0 * 8);
    async16(g2 + bo1, d2 + c1 * 8);
    if (++tn == ksteps) {
      tn = 0; ++pn;
      if (pn == 1) { An = Aa1; Bn = Ba1; Cn = Ca1; }
      else if (pn == 2) { An = Aa2; Bn = Ba2; Cn = Ca2; }
    }
  };

  issue(0);
  issue(1);
  int slot = 0;
  for (int i = 0; i < total; ++i) {
    if (i + 1 < total) asm volatile("s_waitcnt vmcnt(6)" ::: "memory");
    else               asm volatile("s_waitcnt vmcnt(0)" ::: "memory");
    __builtin_amdgcn_sched_barrier(0);
    __builtin_amdgcn_s_barrier();
    __builtin_amdgcn_sched_barrier(0);
    if (i + 2 < total) {
      int s2 = slot + 2; if (s2 >= 3) s2 -= 3;
      issue(s2);
    }
    const u16* Sa = As + slot * 4096;
    const u16* S1 = B1s + slot * 4096;
    const u16* S2 = B2s + slot * 4096;
    bf16x8 af[4], b1v[4], b2v[4];
#pragma unroll
    for (int k = 0; k < 4; ++k) af[k] = *(const bf16x8*)(Sa + aoffs[k]);
#pragma unroll
    for (int k = 0; k < 4; ++k) b1v[k] = *(const bf16x8*)(S1 + boffs[k]);
#pragma unroll
    for (int k = 0; k < 4; ++k) b2v[k] = *(const bf16x8*)(S2 + boffs[k]);
#pragma unroll
    for (int mi = 0; mi < 4; ++mi)
#pragma unroll
      for (int nj = 0; nj < 4; ++nj)
        a1[mi][nj] = __builtin_amdgcn_mfma_f32_16x16x32_bf16(
            af[mi], b1v[nj], a1[mi][nj], 0, 0, 0);
#pragma unroll
    for (int mi = 0; mi < 4; ++mi)
#pragma unroll
      for (int nj = 0; nj < 4; ++nj)
        a2[mi][nj] = __builtin_amdgcn_mfma_f32_16x16x32_bf16(
            af[mi], b2v[nj], a2[mi][nj], 0, 0, 0);
    if (++slot == 3) slot = 0;
  }
}

#define GEMM_EPI_IDX                                                    \
  const int lane = threadIdx.x & 63, wv = threadIdx.x >> 6;             \
  const int wr = (wv >> 1) * 64, wc = (wv & 1) * 64;                    \
  const int mcol = lane & 15, q = lane >> 4;                            \
  const int gm0 = by * 128, gn0 = bx * 128;

// fa1+fa2 fused, 3-pass dual-B.
__global__ __launch_bounds__(256) void k_gemm_fa12(const u16* Ah, const u16* Al,
    const u16* W1h, const u16* W1l, const u16* W2h, const u16* W2l,
    const float* bias, u16* Chi, u16* Clo) {
  __shared__ __align__(16) u16 As[12288], B1s[12288], B2s[12288];
  int bx, by; swz_xy(bx, by);
  const size_t arow = (size_t)by * 128 * 1280;
  const size_t wrow = (size_t)bx * 128 * 640;
  const u16* Aph[3]  = {Ah + arow, Al + arow, Ah + arow};
  const u16* B1ph[3] = {W1h + wrow, W1h + wrow, W1l + wrow};
  const u16* B2ph[3] = {W2h + wrow, W2h + wrow, W2l + wrow};
  f32x4 a1[4][4] = {}, a2[4][4] = {};
  gemm_core2(Aph, B1ph, B2ph, 1280, 640, 20, As, B1s, B2s, a1, a2);
  GEMM_EPI_IDX
#pragma unroll
  for (int mi = 0; mi < 4; ++mi)
#pragma unroll
    for (int r = 0; r < 4; ++r) {
      int grow = gm0 + wr + mi * 16 + q * 4 + r;
#pragma unroll
      for (int ni = 0; ni < 4; ++ni) {
        int gcol = gn0 + wc + ni * 16 + mcol;
        float v1 = fmaxf(a1[mi][ni][r] + bias[gcol], 0.f);
        float v2 = fmaxf(a2[mi][ni][r] + bias[640 + gcol], 0.f);
        float y = v1 * v2;
        u16 h = f2bf(y);
        Chi[(size_t)grow * 1280 + 640 + gcol] = h;
        Clo[(size_t)grow * 1280 + 640 + gcol] = f2bf(y - bf2f(h));
      }
    }
}

// lp: [512,2048] @ [2560,2048]^T, fused 3-product, relu -> f32 [512,2560]
__global__ __launch_bounds__(256) void k_gemm_lp(const u16* Ah, const u16* Al,
    const u16* Wh, const u16* Wl, const float* bias, float* outp) {
  __shared__ __align__(16) u16 S[32768];
  int bx, by; swz_xy(bx, by);
  const size_t arow = (size_t)by * 128 * 2048;
  const size_t wrow = (size_t)bx * 128 * 2048;
  f32x4 acc[4][4] = {};
  gemm_fused3(Ah + arow, Al + arow, Wh + wrow, Wl + wrow, 2048, 2048, 64, S,
              acc);
  GEMM_EPI_IDX
#pragma unroll
  for (int mi = 0; mi < 4; ++mi)
#pragma unroll
    for (int r = 0; r < 4; ++r) {
      int grow = gm0 + wr + mi * 16 + q * 4 + r;
#pragma unroll
      for (int ni = 0; ni < 4; ++ni) {
        int gcol = gn0 + wc + ni * 16 + mcol;
        outp[(size_t)grow * 2560 + gcol] = fmaxf(acc[mi][ni][r] + bias[gcol], 0.f);
      }
    }
}

// ================== fa3+fa4: 256^2 8-wave core, R9 ==================
// R9: intra-step barriers removed. Within a K-step all ds_reads hit
// S[cur] and all DMA writes hit S[cur^1] -- no cross-wave hazard exists,
// so the per-phase barriers of R6 were pure overhead (17 barrier ops ->
// 1 per step). Waves free-run through the step (2 waves/SIMD interleave
// naturally; setprio arbitrates MFMA clusters); the single step-boundary
// sync is vmcnt(0) (own DMA drained) + s_barrier (all waves' writes
// visible) before swapping buffers.
__global__ __launch_bounds__(512, 2) void k_gemm_fa34(const u16* Ah,
    const u16* Al, const u16* Wh, const u16* Wl, const float* b34,
    const float* lp_o, u16* fa3h, u16* fa3l, u16* fa4h, u16* fa4l, int r0) {
  __shared__ __align__(16) u16 S[2][4][8192];  // [buf][Ah,Al,Bh,Bl][256*32]
  int bx, by; swz_xy(bx, by);  // grid (10, RN/256)
  const int tid = threadIdx.x;
  const int lane = tid & 63, wv = tid >> 6;
  const int wm = wv >> 2, wn = wv & 3;
  const int mrow = lane & 15, q = lane >> 4;

  const size_t arow = (size_t)by * 256 * 1280;
  const size_t wrow = (size_t)bx * 256 * 1280;
  const u16* mats[4] = {Ah + arow, Al + arow, Wh + wrow, Wl + wrow};

  long soff[2];
#pragma unroll
  for (int j = 0; j < 2; ++j) {
    const int c = j * 512 + tid;
    soff[j] = (long)(c >> 2) * 1280 + ((c & 3) ^ ((c >> 3) & 3)) * 8;
  }
  int aoffs[8], boffs[4];
#pragma unroll
  for (int k = 0; k < 8; ++k) {
    const int r = wm * 128 + k * 16 + mrow;
    aoffs[k] = r * 32 + ((q ^ ((r >> 1) & 3)) << 3);
  }
#pragma unroll
  for (int k = 0; k < 4; ++k) {
    const int r = wn * 64 + k * 16 + mrow;
    boffs[k] = r * 32 + ((q ^ ((r >> 1) & 3)) << 3);
  }

  f32x4 acc[8][4] = {};
  const int ks = 40;  // K=1280 / 32

#pragma unroll
  for (int m = 0; m < 4; ++m) {
    async16(mats[m] + soff[0], &S[0][m][tid * 8]);
    async16(mats[m] + soff[1], &S[0][m][(512 + tid) * 8]);
  }
  asm volatile("s_waitcnt vmcnt(0)" ::: "memory");
  __builtin_amdgcn_sched_barrier(0);
  __builtin_amdgcn_s_barrier();
  __builtin_amdgcn_sched_barrier(0);

  for (int t = 0; t < ks; ++t) {
    const int cur = t & 1;
    const long ta = (long)(t + 1) * 32;
    const bool more = (t + 1 < ks);
    bf16x8 bh[4], bl[4];
#pragma unroll
    for (int k = 0; k < 4; ++k) {
      bh[k] = *(const bf16x8*)(&S[cur][2][0] + boffs[k]);
      bl[k] = *(const bf16x8*)(&S[cur][3][0] + boffs[k]);
    }
#pragma unroll
    for (int p = 0; p < 8; ++p) {
      bf16x8 ah = *(const bf16x8*)(&S[cur][0][0] + aoffs[p]);
      bf16x8 al = *(const bf16x8*)(&S[cur][1][0] + aoffs[p]);
      if (p < 4 && more) {
        async16(mats[p] + ta + soff[0], &S[cur ^ 1][p][tid * 8]);
        async16(mats[p] + ta + soff[1], &S[cur ^ 1][p][(512 + tid) * 8]);
      }
      __builtin_amdgcn_s_setprio(1);
#pragma unroll
      for (int j = 0; j < 4; ++j)
        acc[p][j] = __builtin_amdgcn_mfma_f32_16x16x32_bf16(ah, bh[j],
                                                            acc[p][j], 0, 0, 0);
#pragma unroll
      for (int j = 0; j < 4; ++j)
        acc[p][j] = __builtin_amdgcn_mfma_f32_16x16x32_bf16(al, bh[j],
                                                            acc[p][j], 0, 0, 0);
#pragma unroll
      for (int j = 0; j < 4; ++j)
        acc[p][j] = __builtin_amdgcn_mfma_f32_16x16x32_bf16(ah, bl[j],
                                                            acc[p][j], 0, 0, 0);
      __builtin_amdgcn_s_setprio(0);
    }
    // step boundary: own DMA drained + all waves arrived -> buf swap safe
    asm volatile("s_waitcnt vmcnt(0)" ::: "memory");
    __builtin_amdgcn_sched_barrier(0);
    __builtin_amdgcn_s_barrier();
    __builtin_amdgcn_sched_barrier(0);
  }

  const int gm0 = by * 256, gn0 = bx * 256;
  const int seg = (gn0 >= 1280);
  u16* dsth = seg ? fa4h : fa3h;
  u16* dstl = seg ? fa4l : fa3l;
#pragma unroll
  for (int p = 0; p < 8; ++p)
#pragma unroll
    for (int r = 0; r < 4; ++r) {
      const int grow = gm0 + wm * 128 + p * 16 + q * 4 + r;
      const int b = (r0 + grow) / 50;
      const float* lpb = lp_o + (size_t)b * 2560;
#pragma unroll
      for (int j = 0; j < 4; ++j) {
        const int gcol = gn0 + wn * 64 + j * 16 + mrow;
        const int c = gcol - seg * 1280;
        float v = fmaxf(acc[p][j][r] + b34[gcol], 0.f);
        if (!seg) v *= lpb[c];
        if (c < 1216) {
          u16 h = f2bf(v);
          dsth[(size_t)grow * 1216 + c] = h;
          dstl[(size_t)grow * 1216 + c] = f2bf(v - bf2f(h));
        }
      }
    }
}

// fa5: 1-pass 128^2 core.
__global__ __launch_bounds__(256) void k_gemm_fa5(const u16* Ah,
    const u16* W5h, const float* b5, const float* lp_o, u16* fa5o, int r0) {
  __shared__ __align__(16) u16 S[32768];
  int bx, by; swz_xy(bx, by);  // grid (10, RN/128)
  const size_t arow = (size_t)by * 128 * 1280;
  const size_t wrow = (size_t)bx * 128 * 1280;
  f32x4 acc[4][4] = {};
  gemm_core1(Ah + arow, W5h + wrow, 1280, 1280, 40, S, S + 16384, acc);
  GEMM_EPI_IDX
#pragma unroll
  for (int mi = 0; mi < 4; ++mi)
#pragma unroll
    for (int r = 0; r < 4; ++r) {
      int grow = gm0 + wr + mi * 16 + q * 4 + r;
      int b = (r0 + grow) / 50;
      const float* lpb = lp_o + (size_t)b * 2560 + 1280;
#pragma unroll
      for (int ni = 0; ni < 4; ++ni) {
        int gcol = gn0 + wc + ni * 16 + mcol;
        float v = fmaxf(acc[mi][ni][r] + b5[gcol], 0.f) * lpb[gcol];
        if (gcol < 1216) fa5o[(size_t)grow * 1216 + gcol] = f2bf(v);
      }
    }
}

// out FC, 1-pass: messages = relu(msg@outw^T+b), masked, -> d_out cols 300..599
__global__ __launch_bounds__(256) void k_gemm_out(const u16* A, const u16* Wh,
    const float* bias, const int* mask_s, float* outp, int r0) {
  __shared__ __align__(16) u16 S[32768];
  int bx, by; swz_xy(bx, by);
  const size_t arow = (size_t)by * 128 * 1216;
  const size_t wrow = (size_t)bx * 128 * 1216;
  f32x4 acc[4][4] = {};
  gemm_core1(A + arow, Wh + wrow, 1216, 1216, 38, S, S + 16384, acc);
  GEMM_EPI_IDX
#pragma unroll
  for (int mi = 0; mi < 4; ++mi)
#pragma unroll
    for (int r = 0; r < 4; ++r) {
      int grow = r0 + gm0 + wr + mi * 16 + q * 4 + r;  // global row
      int b = grow / 50;
      int n = grow - b * 50;
      float keep = (n < mask_s[b]) ? 1.f : 0.f;
#pragma unroll
      for (int ni = 0; ni < 4; ++ni) {
        int gcol = gn0 + wc + ni * 16 + mcol;
        float v = fmaxf(acc[mi][ni][r] + bias[gcol], 0.f) * keep;
        if (gcol < 300) outp[(size_t)grow * 600 + 300 + gcol] = v;
      }
    }
}

// ============================ attention ============================
// (R6 256-thread version -- R8's 512-thread variant regressed.)
__global__ __launch_bounds__(256) void k_attn(const u16* fa3h, const u16* fa3l,
    const u16* fa4h, const u16* fa4l, const u16* fa5o, const int* mask_s,
    float* adj_out, u16* msg, int b0) {
  __shared__ __align__(16) u16 stg[32768];  // 8 slots x 8KB
  __shared__ float Ssc[64 * 64];
  const int bl = blockIdx.x;
  const int bg = b0 + bl;
  const int tid = threadIdx.x, lane = tid & 63, wv = tid >> 6;
  const int mrow = lane & 15, q = lane >> 4;
  const size_t base = (size_t)bl * 50 * 1216;

  // ---- phase 1: logits (3 passes flattened: h*h, l*h, h*l) ----
  {
    const int srow = tid >> 2;
    const int srcRow = srow < 50 ? srow : 49;
    const size_t gsoff = base + (size_t)srcRow * 1216 +
                         (size_t)(((tid & 3) ^ ((tid >> 3) & 3)) * 8);
    auto issueP1 = [&](int sl, int s) {
      const int p = (s >= 76) ? 2 : (s >= 38 ? 1 : 0);
      const int t = s - p * 38;
      const u16* Ap = (p == 1) ? fa4l : fa4h;
      const u16* Bp = (p == 2) ? fa3l : fa3h;
      u16* d = stg + sl * 4096;
      async16(Ap + gsoff + (size_t)t * 32, d + tid * 8);
      async16(Bp + gsoff + (size_t)t * 32, d + 2048 + tid * 8);
    };
    const int ra = wv * 16 + mrow;
    const int aoff = ra * 32 + ((q ^ ((ra >> 1) & 3)) << 3);
    int boff[4];
#pragma unroll
    for (int ni = 0; ni < 4; ++ni) {
      const int rb = ni * 16 + mrow;
      boff[ni] = rb * 32 + ((q ^ ((rb >> 1) & 3)) << 3);
    }
    for (int j = 0; j < 7; ++j) issueP1(j, j);
    f32x4 acc[4] = {};
    int cs = 0, is = 7;
    for (int i = 0; i < 114; ++i) {
      const int rem = 113 - i;
      if (rem >= 6)      asm volatile("s_waitcnt vmcnt(12)" ::: "memory");
      else if (rem == 5) asm volatile("s_waitcnt vmcnt(10)" ::: "memory");
      else if (rem == 4) asm volatile("s_waitcnt vmcnt(8)" ::: "memory");
      else if (rem == 3) asm volatile("s_waitcnt vmcnt(6)" ::: "memory");
      else if (rem == 2) asm volatile("s_waitcnt vmcnt(4)" ::: "memory");
      else if (rem == 1) asm volatile("s_waitcnt vmcnt(2)" ::: "memory");
      else               asm volatile("s_waitcnt vmcnt(0)" ::: "memory");
      __builtin_amdgcn_sched_barrier(0);
      __builtin_amdgcn_s_barrier();
      __builtin_amdgcn_sched_barrier(0);
      if (i + 7 < 114) { issueP1(is, i + 7); if (++is == 8) is = 0; }
      const u16* d = stg + cs * 4096;
      if (++cs == 8) cs = 0;
      bf16x8 af = *(const bf16x8*)(d + aoff);
#pragma unroll
      for (int ni = 0; ni < 4; ++ni) {
        bf16x8 bv = *(const bf16x8*)(d + 2048 + boff[ni]);
        acc[ni] =
            __builtin_amdgcn_mfma_f32_16x16x32_bf16(af, bv, acc[ni], 0, 0, 0);
      }
    }
#pragma unroll
    for (int ni = 0; ni < 4; ++ni)
#pragma unroll
      for (int r = 0; r < 4; ++r)
        Ssc[(wv * 16 + q * 4 + r) * 64 + ni * 16 + mrow] = acc[ni][r];
  }
  __syncthreads();

  // ---- phase-3 staging geometry (needed for early prologue) ----
  const int c0 = tid, c1 = tid + 256;
  const int m0 = c0 >> 3, d0 = (c0 & 7) * 8;
  const int m1 = c1 >> 3, d1 = (c1 & 7) * 8;
  const size_t g0 = base + (size_t)(m0 < 50 ? m0 : 49) * 1216 + d0;
  const size_t g1 = base + (size_t)(m1 < 50 ? m1 : 49) * 1216 + d1;
  auto issueP3 = [&](int sl, int s) {
    u16* d = stg + sl * 4096;
    async16(fa5o + g0 + (size_t)s * 64, d + c0 * 8);
    async16(fa5o + g1 + (size_t)s * 64, d + c1 * 8);
  };
  for (int j = 0; j < 7; ++j) issueP3(j, j);

  // ---- phase 2: mask + softmax, write adj ----
  {
    const int mk = mask_s[bg];
    for (int n = wv; n < 50; n += 4) {
      int mm = lane;
      float v = -__builtin_inff();
      if (mm < 50) {
        int mx2 = n > mm ? n : mm;
        bool valid = (mx2 < mk) || (n >= mk);
        if (mm == n) valid = false;
        if (n == 0 && mm == 0 && mk == 1) valid = true;
        if (valid) v = Ssc[n * 64 + mm];
      }
      float mx = v;
      for (int o = 32; o > 0; o >>= 1) mx = fmaxf(mx, __shfl_down(mx, o));
      mx = __shfl(mx, 0);
      float e = __expf(v - mx);
      float sm = e;
      for (int o = 32; o > 0; o >>= 1) sm += __shfl_down(sm, o);
      sm = __shfl(sm, 0);
      float pv = e / sm;
      if (mm < 50) {
        adj_out[((size_t)bg * 50 + n) * 50 + mm] = pv;
        Ssc[n * 64 + mm] = pv;
      } else {
        Ssc[n * 64 + mm] = 0.f;
      }
    }
  }
  __syncthreads();

  // ---- phase 3: msg[n][d] = sum_m adj[n][m] * fa5o[m][d] ----
  {
    int cs = 0, is = 7;
    for (int dt = 0; dt < 19; ++dt) {
      const int rem = 18 - dt;
      if (rem >= 6)      asm volatile("s_waitcnt vmcnt(12)" ::: "memory");
      else if (rem == 5) asm volatile("s_waitcnt vmcnt(10)" ::: "memory");
      else if (rem == 4) asm volatile("s_waitcnt vmcnt(8)" ::: "memory");
      else if (rem == 3) asm volatile("s_waitcnt vmcnt(6)" ::: "memory");
      else if (rem == 2) asm volatile("s_waitcnt vmcnt(4)" ::: "memory");
      else if (rem == 1) asm volatile("s_waitcnt vmcnt(2)" ::: "memory");
      else               asm volatile("s_waitcnt vmcnt(0)" ::: "memory");
      __builtin_amdgcn_sched_barrier(0);
      __builtin_amdgcn_s_barrier();
      __builtin_amdgcn_sched_barrier(0);
      if (dt + 7 < 19) { issueP3(is, dt + 7); if (++is == 8) is = 0; }
      const u16* d = stg + cs * 4096;
      if (++cs == 8) cs = 0;
      f32x4 a3[4] = {};
#pragma unroll
      for (int ks = 0; ks < 2; ++ks) {
        bf16x8 af;
#pragma unroll
        for (int j = 0; j < 8; ++j)
          af[j] = (__bf16)Ssc[(wv * 16 + mrow) * 64 + ks * 32 + q * 8 + j];
#pragma unroll
        for (int ni = 0; ni < 4; ++ni) {
          bf16x8 bv;
#pragma unroll
          for (int j = 0; j < 8; ++j)
            bv[j] = *(const __bf16*)(d + (ks * 32 + q * 8 + j) * 64 + ni * 16 + mrow);
          a3[ni] = __builtin_amdgcn_mfma_f32_16x16x32_bf16(af, bv, a3[ni], 0, 0, 0);
        }
      }
#pragma unroll
      for (int ni = 0; ni < 4; ++ni)
#pragma unroll
        for (int r = 0; r < 4; ++r) {
          int n = wv * 16 + q * 4 + r;
          if (n < 50)
            msg[((size_t)bl * 50 + n) * 1216 + dt * 64 + ni * 16 + mrow] =
                f2bf(a3[ni][r]);
        }
    }
  }
}

// ============================ host ============================
extern "C" void kernel_launch(void* const* d_in, const int* in_sizes, int n_in,
                              void* d_out_, int out_size, void* d_ws,
                              size_t ws_size, hipStream_t stream) {
  (void)in_sizes; (void)n_in; (void)out_size;
  const float* l_in = (const float*)d_in[0];
  const float* s_in = (const float*)d_in[1];
  const float* ps   = (const float*)d_in[2];
  const int*   msk  = (const int*)d_in[3];
  const float* bbw  = (const float*)d_in[4];
  const float* bbb  = (const float*)d_in[5];
  const float* fa1w = (const float*)d_in[6];
  const float* fa1b = (const float*)d_in[7];
  const float* fa2w = (const float*)d_in[8];
  const float* fa2b = (const float*)d_in[9];
  const float* fa3w = (const float*)d_in[10];
  const float* fa3b = (const float*)d_in[11];
  const float* fa4w = (const float*)d_in[12];
  const float* fa4b = (const float*)d_in[13];
  const float* fa5w = (const float*)d_in[14];
  const float* fa5b = (const float*)d_in[15];
  const float* lp1w = (const float*)d_in[16];
  const float* lp1b = (const float*)d_in[17];
  const float* lp2w = (const float*)d_in[18];
  const float* lp2b = (const float*)d_in[19];
  const float* outw = (const float*)d_in[20];
  const float* outb = (const float*)d_in[21];
  float* outp = (float*)d_out_;

  char* wsb = (char*)d_ws;
  size_t off = 0;
  auto alloc = [&](size_t bytes) -> char* {
    char* p = wsb + off;
    off = (off + bytes + 255) & ~(size_t)255;
    return p;
  };
  // ---- persistent (~31 MB) ----
  u16*   l_hi   = (u16*)alloc(512ull * 2048 * 2);
  u16*   l_lo   = (u16*)alloc(512ull * 2048 * 2);
  u16*   Wout   = (u16*)alloc(384ull * 1216 * 2);
  float* b_fa12 = (float*)alloc(1280 * 4);
  float* b_fa34 = (float*)alloc(2560 * 4);
  float* b_fa5  = (float*)alloc(1280 * 4);
  float* b_lp   = (float*)alloc(2560 * 4);
  float* b_out  = (float*)alloc(384 * 4);
  float* lp_o   = (float*)alloc(512ull * 2560 * 4);
  // weight slab, time-shared: lp weights -> fa* weights (stream-ordered).
  u16*   slab   = (u16*)alloc(10485760ull * 2);
  u16* Wlph   = slab;                  // 2560x2048
  u16* Wlpl   = slab + 5242880;        // 2560x2048
  u16* Wfa1h  = slab;                  // 640x640
  u16* Wfa1l  = slab + 409600;
  u16* Wfa2h  = slab + 819200;
  u16* Wfa2l  = slab + 1228800;
  u16* Wfa34h = slab + 1638400;        // 2560x1280
  u16* Wfa34l = slab + 4915200;        // 2560x1280
  u16* Wfa5h  = slab + 8192000;        // 1280x1280

  // chunk rows RN (must be multiple of 256 for the fa34 grid)
  size_t ws_eff = ws_size ? ws_size : (size_t)512 * 1024 * 1024;
  long RN = 6400;
  const long opts[3] = {25600, 12800, 6400};
  for (int i = 0; i < 3; ++i) {
    size_t need = off + (size_t)17280 * opts[i] + 8 * 256;
    if (need <= ws_eff) { RN = opts[i]; break; }
  }
  u16*  Chi  = (u16*)alloc((size_t)RN * 1280 * 2);
  u16*  Clo  = (u16*)alloc((size_t)RN * 1280 * 2);
  u16*  fa5o = (u16*)alloc((size_t)RN * 1216 * 2);
  u16*  fa3h = (u16*)alloc((size_t)RN * 1216 * 2);
  u16*  fa3l = (u16*)alloc((size_t)RN * 1216 * 2);
  u16*  fa4h = (u16*)alloc((size_t)RN * 1216 * 2);
  u16*  fa4l = (u16*)alloc((size_t)RN * 1216 * 2);
  u16*  msg  = Chi;  // combined dead after fa34/fa5; reuse for messages_in
  float* adj_o = outp + 15360000;

  dim3 T(256);
  // biases (padded)
  k_pack_bias<<<dim3(3), T, 0, stream>>>(fa1b, 600, b_fa12, 640);
  k_pack_bias<<<dim3(3), T, 0, stream>>>(fa2b, 600, b_fa12 + 640, 640);
  k_pack_bias<<<dim3(5), T, 0, stream>>>(fa3b, 1200, b_fa34, 1280);
  k_pack_bias<<<dim3(5), T, 0, stream>>>(fa4b, 1200, b_fa34 + 1280, 1280);
  k_pack_bias<<<dim3(5), T, 0, stream>>>(fa5b, 1200, b_fa5, 1280);
  k_pack_bias<<<dim3(5), T, 0, stream>>>(lp1b, 1200, b_lp, 1280);
  k_pack_bias<<<dim3(5), T, 0, stream>>>(lp2b, 1200, b_lp + 1280, 1280);
  k_pack_bias<<<dim3(2), T, 0, stream>>>(outb, 300, b_out, 384);

  auto packw = [&](const float* src, int n, int k, u16* hi, u16* lo, int KP,
                   long total, int gap) {
    k_pack_w<<<dim3((unsigned)((total + 255) / 256)), T, 0, stream>>>(
        src, n, k, hi, lo, KP, total, gap);
  };
  // static packs
  packw(l_in, 512, 2048, l_hi, l_lo, 2048, 512L * 2048, 0);
  packw(outw, 300, 1200, Wout, nullptr, 1216, 384L * 1216, 0);

  // lp stage
  packw(lp1w, 1200, 2048, Wlph, Wlpl, 2048, 1280L * 2048, 0);
  packw(lp2w, 1200, 2048, Wlph + 1280 * 2048, Wlpl + 1280 * 2048, 2048,
        1280L * 2048, 0);
  k_gemm_lp<<<dim3(20, 4), T, 0, stream>>>(l_hi, l_lo, Wlph, Wlpl, b_lp, lp_o);

  // fa weights into slab (lp weights dead after k_gemm_lp)
  packw(fa1w, 600, 600, Wfa1h, Wfa1l, 640, 640L * 640, 0);
  packw(fa2w, 600, 600, Wfa2h, Wfa2l, 640, 640L * 640, 0);
  packw(fa3w, 1200, 1200, Wfa34h, Wfa34l, 1280, 1280L * 1280, 1);
  packw(fa4w, 1200, 1200, Wfa34h + 1638400, Wfa34l + 1638400, 1280,
        1280L * 1280, 1);
  packw(fa5w, 1200, 1200, Wfa5h, nullptr, 1280, 1280L * 1280, 1);

  // ---- chunk loop ----
  const int nch = (int)(25600 / RN);
  const unsigned gy = (unsigned)(RN / 128);
  for (int c = 0; c < nch; ++c) {
    const int r0 = (int)(c * RN);
    const int b0 = r0 / 50;
    k_bb<<<dim3((unsigned)RN), T, 0, stream>>>(s_in + (size_t)r0 * 300,
                                               ps + (size_t)r0 * 4, bbw, bbb,
                                               msk, Chi, Clo, outp, r0);
    k_gemm_fa12<<<dim3(5, gy), T, 0, stream>>>(Chi, Clo, Wfa1h, Wfa1l, Wfa2h,
                                               Wfa2l, b_fa12, Chi, Clo);
    k_gemm_fa34<<<dim3(10, (unsigned)(RN / 256)), dim3(512), 0, stream>>>(
        Chi, Clo, Wfa34h, Wfa34l, b_fa34, lp_o, fa3h, fa3l, fa4h, fa4l, r0);
    k_gemm_fa5<<<dim3(10, gy), T, 0, stream>>>(Chi, Wfa5h, b_fa5, lp_o, fa5o,
                                               r0);
    k_attn<<<dim3((unsigned)(RN / 50)), T, 0, stream>>>(fa3h, fa3l, fa4h, fa4l,
                                                        fa5o, msk, adj_o, msg,
                                                        b0);
    k_gemm_out<<<dim3(3, gy), T, 0, stream>>>(msg, Wout, b_out, msk, outp, r0);
  }
}